// Round 6
// baseline (1392.217 us; speedup 1.0000x reference)
//
#include <hip/hip_runtime.h>
#include <cstdint>

typedef short bf16x8 __attribute__((ext_vector_type(8)));
typedef float f32x4  __attribute__((ext_vector_type(4)));

#define TOK    64         // tokens per block
#define CHUNK  32         // codes per chunk
#define PITCH  264        // ushorts/row (256 + 8 pad; 132 dw = 4 mod 32 -> b128 tiles banks)
#define QSTRIDE (32 * PITCH)   // ushorts per quarter chunk-buffer
#define MAXC   16

__device__ __forceinline__ unsigned short f2bf(float f) {
  unsigned u = __float_as_uint(f);
  return (unsigned short)((u + 0x7FFFu + ((u >> 16) & 1u)) >> 16);
}
__device__ __forceinline__ uint4 pack8(float4 a, float4 b) {
  uint4 u;
  u.x = (unsigned)f2bf(a.x) | ((unsigned)f2bf(a.y) << 16);
  u.y = (unsigned)f2bf(a.z) | ((unsigned)f2bf(a.w) << 16);
  u.z = (unsigned)f2bf(b.x) | ((unsigned)f2bf(b.y) << 16);
  u.w = (unsigned)f2bf(b.z) | ((unsigned)f2bf(b.w) << 16);
  return u;
}

// ---------------------------------------------------------------------------
// Prep: cb_bf = bf16(cb), ee = ||cb_k||^2, een = sqrt(ee). Block 0 zeroes the
// global accumulators (runs before vq_main by stream order -> no memset).
// ---------------------------------------------------------------------------
__global__ __launch_bounds__(256) void vq_prep(const float* __restrict__ cb,
                                               unsigned short* __restrict__ cb_bf,
                                               float* __restrict__ ee,
                                               float* __restrict__ een,
                                               float* __restrict__ acc2,
                                               int* __restrict__ done_ctr, int K) {
  if (blockIdx.x == 0 && threadIdx.x == 0) {
    acc2[0] = 0.f; acc2[1] = 0.f; *done_ctr = 0;
  }
  int wave = threadIdx.x >> 6, lane = threadIdx.x & 63;
  int k = blockIdx.x * 4 + wave;
  if (k >= K) return;
  float4 v = *reinterpret_cast<const float4*>(cb + (size_t)k * 256 + lane * 4);
  float s = v.x * v.x + v.y * v.y + v.z * v.z + v.w * v.w;
  #pragma unroll
  for (int off = 32; off; off >>= 1) s += __shfl_down(s, off, 64);
  ushort4 b;
  b.x = f2bf(v.x); b.y = f2bf(v.y); b.z = f2bf(v.z); b.w = f2bf(v.w);
  *reinterpret_cast<ushort4*>(cb_bf + (size_t)k * 256 + lane * 4) = b;
  if (lane == 0) { ee[k] = s; een[k] = sqrtf(s); }
}

// ---------------------------------------------------------------------------
// Main: 512 thr (8 waves) / 64 tokens / block; grid 512 = 2 blocks/CU =
// 4 waves/SIMD. Wave w: token-pair p=w&1 (32 tokens = 2 A-sets in registers),
// K-quarter qt=w>>1 (256 codes as 8 chunks of 32). Each B-frag read feeds 2
// MFMAs; B-frags shared across the quarter's 2 waves via LDS.
// bf16 screen -> gated LDS candidate list -> exact fp32 rescore (indices are
// pure-fp32-derived) -> epilogue.
// ---------------------------------------------------------------------------
__global__ __launch_bounds__(512, 4) void vq_main(
    const float* __restrict__ z, const float* __restrict__ cb,
    const unsigned short* __restrict__ cb_bf, const float* __restrict__ ee,
    const float* __restrict__ een, const float* __restrict__ mask,
    float* __restrict__ out_q, float* __restrict__ out_idx_f,
    float* __restrict__ out_loss, float* __restrict__ acc2,
    int* __restrict__ done_ctr, int nblocks, int K) {
  __shared__ __align__(16) unsigned short buf[128 * PITCH];  // 67584 B: z-stage, then 4 quarter bufs
  __shared__ float ee_lds[1024];
  __shared__ float een_lds[1024];
  __shared__ float znorm[TOK];
  __shared__ int   ccnt[TOK];
  __shared__ unsigned short cand[TOK * MAXC];
  __shared__ float red[16];
  __shared__ bool  last;

  const int t = threadIdx.x;
  const int n0 = blockIdx.x * TOK;
  const int q16 = t & 15;

  // ---- all code norms into LDS (coalesced) ----
  ee_lds[t]        = ee[t];
  ee_lds[t + 512]  = ee[t + 512];
  een_lds[t]       = een[t];
  een_lds[t + 512] = een[t + 512];
  if (t < TOK) ccnt[t] = 0;

  // ---- stage z -> bf16 into buf rows 0..63 (z reused later as A-frags only) ----
  // 512 thr, 16 lanes/row -> 32 rows/pass, 2 passes over 64 rows.
  #pragma unroll
  for (int pass = 0; pass < 2; ++pass) {
    int row = pass * 32 + (t >> 4);
    const float* zr = z + (size_t)(n0 + row) * 256;
    float ssq = 0.f;
    #pragma unroll
    for (int j = 0; j < 2; ++j) {
      float4 a = *reinterpret_cast<const float4*>(zr + q16 * 8 + j * 128);
      float4 b = *reinterpret_cast<const float4*>(zr + q16 * 8 + j * 128 + 4);
      ssq += a.x*a.x + a.y*a.y + a.z*a.z + a.w*a.w
           + b.x*b.x + b.y*b.y + b.z*b.z + b.w*b.w;
      *reinterpret_cast<uint4*>(&buf[row * PITCH + q16 * 8 + j * 128]) = pack8(a, b);
    }
    #pragma unroll
    for (int off = 1; off < 16; off <<= 1) ssq += __shfl_xor(ssq, off, 64);
    if (q16 == 0) znorm[row] = sqrtf(ssq);
  }
  __syncthreads();

  // ---- A fragments into registers: wave w -> tokens [32p, 32p+32) ----
  const int wv = t >> 6, lane = t & 63;
  const int p = wv & 1, qt = wv >> 1;
  const int quad = lane >> 4, l15 = lane & 15;
  bf16x8 afrag[2][8];
  float  znreg[2][4];
  #pragma unroll
  for (int s = 0; s < 2; ++s) {
    const unsigned short* za = &buf[(p * 32 + s * 16 + l15) * PITCH + quad * 8];
    #pragma unroll
    for (int kk = 0; kk < 8; ++kk)
      afrag[s][kk] = *reinterpret_cast<const bf16x8*>(za + kk * 32);
    #pragma unroll
    for (int r = 0; r < 4; ++r)
      znreg[s][r] = znorm[p * 32 + s * 16 + quad * 4 + r];
  }
  __syncthreads();  // everyone's A-loads done before chunk staging overwrites buf

  float amin[2][4];
  #pragma unroll
  for (int s = 0; s < 2; ++s)
    #pragma unroll
    for (int r = 0; r < 4; ++r) amin[s][r] = 3.4e38f;

  // quarter staging identity: 128 threads (waves 2qt, 2qt+1)
  const int tq  = (p << 6) | lane;        // 0..127 within quarter-group
  const int sq16 = tq & 15, srow = tq >> 4; // 16 lanes/row, 8 rows/pass
  unsigned short* qbuf = &buf[qt * QSTRIDE];

  // ---- chunk loop: 8 chunks of 32 codes per quarter ----
  for (int lc = 0; lc < 8; ++lc) {
    const int kbase = qt * 256 + lc * 32;
    // stage this chunk (single-buffered; cross-block waves hide the barrier)
    #pragma unroll
    for (int pass = 0; pass < 4; ++pass) {
      int row = pass * 8 + srow;          // 0..31
      const unsigned short* src = cb_bf + (size_t)(kbase + row) * 256;
      #pragma unroll
      for (int j = 0; j < 2; ++j) {
        uint4 v = *reinterpret_cast<const uint4*>(src + sq16 * 8 + j * 128);
        *reinterpret_cast<uint4*>(&qbuf[row * PITCH + sq16 * 8 + j * 128]) = v;
      }
    }
    __syncthreads();

    f32x4 acc[2][2];
    #pragma unroll
    for (int s = 0; s < 2; ++s) { acc[s][0] = (f32x4){0,0,0,0}; acc[s][1] = (f32x4){0,0,0,0}; }
    #pragma unroll
    for (int kk = 0; kk < 8; ++kk) {
      bf16x8 b0 = *reinterpret_cast<const bf16x8*>(&qbuf[(l15)      * PITCH + quad * 8 + kk * 32]);
      bf16x8 b1 = *reinterpret_cast<const bf16x8*>(&qbuf[(16 + l15) * PITCH + quad * 8 + kk * 32]);
      acc[0][0] = __builtin_amdgcn_mfma_f32_16x16x32_bf16(afrag[0][kk], b0, acc[0][0], 0, 0, 0);
      acc[1][0] = __builtin_amdgcn_mfma_f32_16x16x32_bf16(afrag[1][kk], b0, acc[1][0], 0, 0, 0);
      acc[0][1] = __builtin_amdgcn_mfma_f32_16x16x32_bf16(afrag[0][kk], b1, acc[0][1], 0, 0, 0);
      acc[1][1] = __builtin_amdgcn_mfma_f32_16x16x32_bf16(afrag[1][kk], b1, acc[1][1], 0, 0, 0);
    }

    float e0  = ee_lds[kbase + l15],  e1  = ee_lds[kbase + 16 + l15];
    float en0 = een_lds[kbase + l15], en1 = een_lds[kbase + 16 + l15];
    #pragma unroll
    for (int s = 0; s < 2; ++s) {
      #pragma unroll
      for (int r = 0; r < 4; ++r) {
        float d0 = e0 - 2.f * acc[s][0][r];
        float d1 = e1 - 2.f * acc[s][1][r];
        float w = fminf(d0, d1);
        #pragma unroll
        for (int off = 1; off < 16; off <<= 1) w = fminf(w, __shfl_xor(w, off, 64));
        float am = fminf(amin[s][r], w);
        amin[s][r] = am;
        int tok = p * 32 + s * 16 + quad * 4 + r;
        float zn = znreg[s][r];
        // margin covers 2-sided bf16 screen error (quarter-local amin: same 2-eps bound)
        if (d0 <= am + 1.5f + 0.002f * zn * en0) {
          int sl = atomicAdd(&ccnt[tok], 1);
          if (sl < MAXC) cand[tok * MAXC + sl] = (unsigned short)(kbase + l15);
        }
        if (d1 <= am + 1.5f + 0.002f * zn * en1) {
          int sl = atomicAdd(&ccnt[tok], 1);
          if (sl < MAXC) cand[tok * MAXC + sl] = (unsigned short)(kbase + 16 + l15);
        }
      }
    }
    __syncthreads();
  }

  // ---- exact fp32 rescore + epilogue: 8 waves x 8 tokens ----
  float lsum = 0.f, msum = 0.f;
  #pragma unroll
  for (int it = 0; it < 8; ++it) {
    int tok = wv * 8 + it;
    int n = n0 + tok;
    float4 zv = *reinterpret_cast<const float4*>(z + (size_t)n * 256 + lane * 4);
    int cnt = ccnt[tok];
    float bs = 3.4e38f; int bk = 0;
    if (cnt > MAXC) {  // overflow fallback: exact scan of all K (safety net)
      for (int k = 0; k < K; ++k) {
        float4 ev = *reinterpret_cast<const float4*>(cb + (size_t)k * 256 + lane * 4);
        float dp = zv.x * ev.x + zv.y * ev.y + zv.z * ev.z + zv.w * ev.w;
        #pragma unroll
        for (int off = 32; off; off >>= 1) dp += __shfl_xor(dp, off, 64);
        float s = ee_lds[k] - 2.f * dp;
        if (s < bs) { bs = s; bk = k; }
      }
    } else {
      for (int c = 0; c < cnt; ++c) {
        int k = cand[tok * MAXC + c];
        float4 ev = *reinterpret_cast<const float4*>(cb + (size_t)k * 256 + lane * 4);
        float dp = zv.x * ev.x + zv.y * ev.y + zv.z * ev.z + zv.w * ev.w;
        #pragma unroll
        for (int off = 32; off; off >>= 1) dp += __shfl_xor(dp, off, 64);
        float s = ee_lds[k] - 2.f * dp;   // identical for all lanes
        if (s < bs || (s == bs && k < bk)) { bs = s; bk = k; }
      }
    }
    float m = mask[n];
    float4 qv = *reinterpret_cast<const float4*>(cb + (size_t)bk * 256 + lane * 4);
    float4 o; o.x = qv.x * m; o.y = qv.y * m; o.z = qv.z * m; o.w = qv.w * m;
    *reinterpret_cast<float4*>(out_q + (size_t)n * 256 + lane * 4) = o;
    float dx = zv.x - qv.x, dy = zv.y - qv.y, dz = zv.z - qv.z, dw = zv.w - qv.w;
    lsum = fmaf(m, dx * dx + dy * dy + dz * dz + dw * dw, lsum);
    if (lane == 0) {
      msum += m;
      out_idx_f[n] = (m > 0.f) ? (float)bk : 0.f;
    }
  }
  #pragma unroll
  for (int off = 32; off; off >>= 1) lsum += __shfl_down(lsum, off, 64);
  if (lane == 0) { red[wv] = lsum; red[8 + wv] = msum; }
  __syncthreads();
  if (t == 0) {
    float a = 0.f, b = 0.f;
    #pragma unroll
    for (int i = 0; i < 8; ++i) { a += red[i]; b += red[8 + i]; }
    atomicAdd(&acc2[0], a);
    atomicAdd(&acc2[1], b);
    __threadfence();
    int prev = atomicAdd(done_ctr, 1);
    last = (prev == nblocks - 1);
  }
  __syncthreads();
  if (last && t == 0) {
    float s  = atomicAdd(&acc2[0], 0.0f);
    float nv = atomicAdd(&acc2[1], 0.0f);
    out_loss[0] = (nv > 0.f) ? (0.25f * s / (nv * 256.0f)) : 0.0f;
  }
}

// ---------------------------------------------------------------------------
extern "C" void kernel_launch(void* const* d_in, const int* in_sizes, int n_in,
                              void* d_out, int out_size, void* d_ws, size_t ws_size,
                              hipStream_t stream) {
  const float* z    = (const float*)d_in[0];  // (N, 256)
  const float* mask = (const float*)d_in[1];  // (N,)
  const float* cb   = (const float*)d_in[2];  // (K, 256)
  const int N = in_sizes[1];                  // 32768
  const int D = 256;
  const int K = in_sizes[2] / D;              // 1024

  float* wsf  = (float*)d_ws;
  float* acc2 = wsf;                          // 2 floats
  int*   dctr = (int*)(wsf + 2);              // 1 int
  float* ee   = wsf + 8;                      // K floats
  float* een  = ee + K;                       // K floats
  unsigned short* cb_bf = (unsigned short*)(een + K);  // K*256 bf16

  float* out_q     = (float*)d_out;           // N*D
  float* out_loss  = out_q + (size_t)N * D;   // 1
  float* out_idx_f = out_loss + 1;            // N

  vq_prep<<<(K + 3) / 4, 256, 0, stream>>>(cb, cb_bf, ee, een, acc2, dctr, K);
  vq_main<<<N / TOK, 512, 0, stream>>>(z, cb, cb_bf, ee, een, mask, out_q,
                                       out_idx_f, out_loss, acc2, dctr, N / TOK, K);
}

// Round 7
// 191.386 us; speedup vs baseline: 7.2744x; 7.2744x over previous
//
#include <hip/hip_runtime.h>
#include <cstdint>

typedef short bf16x8 __attribute__((ext_vector_type(8)));
typedef float f32x4  __attribute__((ext_vector_type(4)));

#define TOK    64         // tokens per block
#define PITCH  264        // ushorts/row (256 + 8 pad; 132 dw = 4 mod 32 -> b128 tiles banks)
#define HROWS  (64 * PITCH)   // one K-half chunk buffer (64 code rows)
#define MAXC   32

__device__ __forceinline__ unsigned short f2bf(float f) {
  unsigned u = __float_as_uint(f);
  return (unsigned short)((u + 0x7FFFu + ((u >> 16) & 1u)) >> 16);
}
__device__ __forceinline__ uint4 pack8(float4 a, float4 b) {
  uint4 u;
  u.x = (unsigned)f2bf(a.x) | ((unsigned)f2bf(a.y) << 16);
  u.y = (unsigned)f2bf(a.z) | ((unsigned)f2bf(a.w) << 16);
  u.z = (unsigned)f2bf(b.x) | ((unsigned)f2bf(b.y) << 16);
  u.w = (unsigned)f2bf(b.z) | ((unsigned)f2bf(b.w) << 16);
  return u;
}

// ---------------------------------------------------------------------------
// Prep: cb_bf = bf16(cb), ee = ||cb_k||^2. Block 0 zeroes global accumulators.
// ---------------------------------------------------------------------------
__global__ __launch_bounds__(256) void vq_prep(const float* __restrict__ cb,
                                               unsigned short* __restrict__ cb_bf,
                                               float* __restrict__ ee,
                                               float* __restrict__ acc2,
                                               int* __restrict__ done_ctr, int K) {
  if (blockIdx.x == 0 && threadIdx.x == 0) {
    acc2[0] = 0.f; acc2[1] = 0.f; *done_ctr = 0;
  }
  int wave = threadIdx.x >> 6, lane = threadIdx.x & 63;
  int k = blockIdx.x * 4 + wave;
  if (k >= K) return;
  float4 v = *reinterpret_cast<const float4*>(cb + (size_t)k * 256 + lane * 4);
  float s = v.x * v.x + v.y * v.y + v.z * v.z + v.w * v.w;
  #pragma unroll
  for (int off = 32; off; off >>= 1) s += __shfl_down(s, off, 64);
  ushort4 b;
  b.x = f2bf(v.x); b.y = f2bf(v.y); b.z = f2bf(v.z); b.w = f2bf(v.w);
  *reinterpret_cast<ushort4*>(cb_bf + (size_t)k * 256 + lane * 4) = b;
  if (lane == 0) ee[k] = s;
}

// ---------------------------------------------------------------------------
// Main: 256 thr (4 waves), TOK=64, grid 512 -> 2 blocks/CU (LDS 76 KB).
// Wave (kh = wv>>1, p = wv&1): tokens [32p, 32p+32) as 2 A-sets IN REGISTERS,
// K-half kh (512 codes = 8 chunks of 64). Per chunk: 32 B-reads -> 64 MFMAs.
// bf16 screen -> half-local-amin gated candidates -> exact fp32 rescore
// (indices pure-fp32-derived) -> epilogue. NO restrictive launch bound:
// R6's (512,4) forced a spill-to-scratch catastrophe (VGPR 64, 1360 us).
// ---------------------------------------------------------------------------
__global__ __launch_bounds__(256, 2) void vq_main(
    const float* __restrict__ z, const float* __restrict__ cb,
    const unsigned short* __restrict__ cb_bf, const float* __restrict__ ee,
    const float* __restrict__ mask,
    float* __restrict__ out_q, float* __restrict__ out_idx_f,
    float* __restrict__ out_loss, float* __restrict__ acc2,
    int* __restrict__ done_ctr, int nblocks, int K) {
  __shared__ __align__(16) unsigned short buf[128 * PITCH];  // 67584 B: z-stage, then 2 half-buffers
  __shared__ float ee_lds[1024];                             // 4 KB
  __shared__ float znorm[TOK];
  __shared__ int   ccnt[TOK];
  __shared__ unsigned short cand[TOK * MAXC];                // 4 KB
  __shared__ float red[8];
  __shared__ bool  last;

  const int t = threadIdx.x;
  const int n0 = blockIdx.x * TOK;
  const int q16 = t & 15;

  // ---- code norms into LDS ----
  ee_lds[t]       = ee[t];
  ee_lds[t + 256] = ee[t + 256];
  ee_lds[t + 512] = ee[t + 512];
  ee_lds[t + 768] = ee[t + 768];
  if (t < TOK) ccnt[t] = 0;

  // ---- stage z -> bf16 into buf rows 0..63; ||z|| ----
  #pragma unroll
  for (int pass = 0; pass < 4; ++pass) {
    int row = pass * 16 + (t >> 4);
    const float* zr = z + (size_t)(n0 + row) * 256;
    float ssq = 0.f;
    #pragma unroll
    for (int j = 0; j < 2; ++j) {
      float4 a = *reinterpret_cast<const float4*>(zr + q16 * 8 + j * 128);
      float4 b = *reinterpret_cast<const float4*>(zr + q16 * 8 + j * 128 + 4);
      ssq += a.x*a.x + a.y*a.y + a.z*a.z + a.w*a.w
           + b.x*b.x + b.y*b.y + b.z*b.z + b.w*b.w;
      *reinterpret_cast<uint4*>(&buf[row * PITCH + q16 * 8 + j * 128]) = pack8(a, b);
    }
    #pragma unroll
    for (int off = 1; off < 16; off <<= 1) ssq += __shfl_xor(ssq, off, 64);
    if (q16 == 0) znorm[row] = sqrtf(ssq);
  }
  __syncthreads();

  // ---- A fragments into registers ----
  const int wv = t >> 6, lane = t & 63;
  const int p = wv & 1, kh = wv >> 1;
  const int quad = lane >> 4, l15 = lane & 15;
  bf16x8 afrag[2][8];
  float  znreg[2][4];
  #pragma unroll
  for (int s = 0; s < 2; ++s) {
    const unsigned short* za = &buf[(p * 32 + s * 16 + l15) * PITCH + quad * 8];
    #pragma unroll
    for (int kk = 0; kk < 8; ++kk)
      afrag[s][kk] = *reinterpret_cast<const bf16x8*>(za + kk * 32);
    #pragma unroll
    for (int r = 0; r < 4; ++r)
      znreg[s][r] = znorm[p * 32 + s * 16 + quad * 4 + r];
  }
  __syncthreads();  // all A-loads done before chunk staging overwrites buf

  float amin[2][4];
  #pragma unroll
  for (int s = 0; s < 2; ++s)
    #pragma unroll
    for (int r = 0; r < 4; ++r) amin[s][r] = 3.4e38f;

  // half-group staging identity: 128 threads (both p-waves of this K-half)
  const int tq = (p << 6) | lane;           // 0..127 within half-group
  const int sq16 = tq & 15, srow = tq >> 4; // 16 lanes/row, 8 rows/pass
  unsigned short* qbuf = &buf[kh * HROWS];

  // ---- chunk loop: 8 chunks x 64 codes per K-half ----
  for (int lc = 0; lc < 8; ++lc) {
    const int kbase = kh * 512 + lc * 64;
    #pragma unroll
    for (int pass = 0; pass < 8; ++pass) {
      int row = pass * 8 + srow;            // 0..63
      const unsigned short* src = cb_bf + (size_t)(kbase + row) * 256;
      #pragma unroll
      for (int j = 0; j < 2; ++j) {
        uint4 v = *reinterpret_cast<const uint4*>(src + sq16 * 8 + j * 128);
        *reinterpret_cast<uint4*>(&qbuf[row * PITCH + sq16 * 8 + j * 128]) = v;
      }
    }
    __syncthreads();

    f32x4 acc[2][4];
    #pragma unroll
    for (int s = 0; s < 2; ++s)
      #pragma unroll
      for (int ct = 0; ct < 4; ++ct) acc[s][ct] = (f32x4){0.f, 0.f, 0.f, 0.f};
    #pragma unroll
    for (int kk = 0; kk < 8; ++kk) {
      bf16x8 b0 = *reinterpret_cast<const bf16x8*>(&qbuf[(l15)      * PITCH + quad * 8 + kk * 32]);
      bf16x8 b1 = *reinterpret_cast<const bf16x8*>(&qbuf[(16 + l15) * PITCH + quad * 8 + kk * 32]);
      bf16x8 b2 = *reinterpret_cast<const bf16x8*>(&qbuf[(32 + l15) * PITCH + quad * 8 + kk * 32]);
      bf16x8 b3 = *reinterpret_cast<const bf16x8*>(&qbuf[(48 + l15) * PITCH + quad * 8 + kk * 32]);
      acc[0][0] = __builtin_amdgcn_mfma_f32_16x16x32_bf16(afrag[0][kk], b0, acc[0][0], 0, 0, 0);
      acc[1][0] = __builtin_amdgcn_mfma_f32_16x16x32_bf16(afrag[1][kk], b0, acc[1][0], 0, 0, 0);
      acc[0][1] = __builtin_amdgcn_mfma_f32_16x16x32_bf16(afrag[0][kk], b1, acc[0][1], 0, 0, 0);
      acc[1][1] = __builtin_amdgcn_mfma_f32_16x16x32_bf16(afrag[1][kk], b1, acc[1][1], 0, 0, 0);
      acc[0][2] = __builtin_amdgcn_mfma_f32_16x16x32_bf16(afrag[0][kk], b2, acc[0][2], 0, 0, 0);
      acc[1][2] = __builtin_amdgcn_mfma_f32_16x16x32_bf16(afrag[1][kk], b2, acc[1][2], 0, 0, 0);
      acc[0][3] = __builtin_amdgcn_mfma_f32_16x16x32_bf16(afrag[0][kk], b3, acc[0][3], 0, 0, 0);
      acc[1][3] = __builtin_amdgcn_mfma_f32_16x16x32_bf16(afrag[1][kk], b3, acc[1][3], 0, 0, 0);
    }

    float e0 = ee_lds[kbase + l15],      e1 = ee_lds[kbase + 16 + l15];
    float e2 = ee_lds[kbase + 32 + l15], e3 = ee_lds[kbase + 48 + l15];
    float en0 = sqrtf(e0), en1 = sqrtf(e1), en2 = sqrtf(e2), en3 = sqrtf(e3);
    #pragma unroll
    for (int s = 0; s < 2; ++s) {
      #pragma unroll
      for (int r = 0; r < 4; ++r) {
        float d0 = e0 - 2.f * acc[s][0][r];
        float d1 = e1 - 2.f * acc[s][1][r];
        float d2 = e2 - 2.f * acc[s][2][r];
        float d3 = e3 - 2.f * acc[s][3][r];
        float w = fminf(fminf(d0, d1), fminf(d2, d3));
        #pragma unroll
        for (int off = 1; off < 16; off <<= 1) w = fminf(w, __shfl_xor(w, off, 64));
        float am = fminf(amin[s][r], w);
        amin[s][r] = am;
        int tok = p * 32 + s * 16 + quad * 4 + r;
        float zn = znreg[s][r];
        // margin >= 2*eps(bf16 screen); half-local amin keeps the same bound
        if (d0 <= am + 1.5f + 0.002f * zn * en0) {
          int sl = atomicAdd(&ccnt[tok], 1);
          if (sl < MAXC) cand[tok * MAXC + sl] = (unsigned short)(kbase + l15);
        }
        if (d1 <= am + 1.5f + 0.002f * zn * en1) {
          int sl = atomicAdd(&ccnt[tok], 1);
          if (sl < MAXC) cand[tok * MAXC + sl] = (unsigned short)(kbase + 16 + l15);
        }
        if (d2 <= am + 1.5f + 0.002f * zn * en2) {
          int sl = atomicAdd(&ccnt[tok], 1);
          if (sl < MAXC) cand[tok * MAXC + sl] = (unsigned short)(kbase + 32 + l15);
        }
        if (d3 <= am + 1.5f + 0.002f * zn * en3) {
          int sl = atomicAdd(&ccnt[tok], 1);
          if (sl < MAXC) cand[tok * MAXC + sl] = (unsigned short)(kbase + 48 + l15);
        }
      }
    }
    __syncthreads();
  }

  // ---- exact fp32 rescore + epilogue: 4 waves x 16 tokens ----
  float lsum = 0.f, msum = 0.f;
  for (int it = 0; it < 16; ++it) {
    int tok = wv * 16 + it;
    int n = n0 + tok;
    float4 zv = *reinterpret_cast<const float4*>(z + (size_t)n * 256 + lane * 4);
    int cnt = ccnt[tok];
    float bs = 3.4e38f; int bk = 0;
    if (cnt > MAXC) {  // overflow safety net: exact scan of all K
      for (int k = 0; k < K; ++k) {
        float4 ev = *reinterpret_cast<const float4*>(cb + (size_t)k * 256 + lane * 4);
        float dp = zv.x * ev.x + zv.y * ev.y + zv.z * ev.z + zv.w * ev.w;
        #pragma unroll
        for (int off = 32; off; off >>= 1) dp += __shfl_xor(dp, off, 64);
        float s = ee_lds[k] - 2.f * dp;
        if (s < bs) { bs = s; bk = k; }
      }
    } else {
      for (int c = 0; c < cnt; ++c) {
        int k = cand[tok * MAXC + c];
        float4 ev = *reinterpret_cast<const float4*>(cb + (size_t)k * 256 + lane * 4);
        float dp = zv.x * ev.x + zv.y * ev.y + zv.z * ev.z + zv.w * ev.w;
        #pragma unroll
        for (int off = 32; off; off >>= 1) dp += __shfl_xor(dp, off, 64);
        float s = ee_lds[k] - 2.f * dp;   // identical on all lanes
        if (s < bs || (s == bs && k < bk)) { bs = s; bk = k; }
      }
    }
    float m = mask[n];
    float4 qv = *reinterpret_cast<const float4*>(cb + (size_t)bk * 256 + lane * 4);
    float4 o; o.x = qv.x * m; o.y = qv.y * m; o.z = qv.z * m; o.w = qv.w * m;
    *reinterpret_cast<float4*>(out_q + (size_t)n * 256 + lane * 4) = o;
    float dx = zv.x - qv.x, dy = zv.y - qv.y, dz = zv.z - qv.z, dw = zv.w - qv.w;
    lsum = fmaf(m, dx * dx + dy * dy + dz * dz + dw * dw, lsum);
    if (lane == 0) {
      msum += m;
      out_idx_f[n] = (m > 0.f) ? (float)bk : 0.f;
    }
  }
  #pragma unroll
  for (int off = 32; off; off >>= 1) lsum += __shfl_down(lsum, off, 64);
  if (lane == 0) { red[wv] = lsum; red[4 + wv] = msum; }
  __syncthreads();
  if (t == 0) {
    atomicAdd(&acc2[0], red[0] + red[1] + red[2] + red[3]);
    atomicAdd(&acc2[1], red[4] + red[5] + red[6] + red[7]);
    __threadfence();
    int prev = atomicAdd(done_ctr, 1);
    last = (prev == nblocks - 1);
  }
  __syncthreads();
  if (last && t == 0) {
    float s  = atomicAdd(&acc2[0], 0.0f);
    float nv = atomicAdd(&acc2[1], 0.0f);
    out_loss[0] = (nv > 0.f) ? (0.25f * s / (nv * 256.0f)) : 0.0f;
  }
}

// ---------------------------------------------------------------------------
extern "C" void kernel_launch(void* const* d_in, const int* in_sizes, int n_in,
                              void* d_out, int out_size, void* d_ws, size_t ws_size,
                              hipStream_t stream) {
  const float* z    = (const float*)d_in[0];  // (N, 256)
  const float* mask = (const float*)d_in[1];  // (N,)
  const float* cb   = (const float*)d_in[2];  // (K, 256)
  const int N = in_sizes[1];                  // 32768
  const int D = 256;
  const int K = in_sizes[2] / D;              // 1024

  float* wsf  = (float*)d_ws;
  float* acc2 = wsf;                          // 2 floats
  int*   dctr = (int*)(wsf + 2);              // 1 int
  float* ee   = wsf + 8;                      // K floats
  unsigned short* cb_bf = (unsigned short*)(ee + K);  // K*256 bf16

  float* out_q     = (float*)d_out;           // N*D
  float* out_loss  = out_q + (size_t)N * D;   // 1
  float* out_idx_f = out_loss + 1;            // N

  vq_prep<<<(K + 3) / 4, 256, 0, stream>>>(cb, cb_bf, ee, acc2, dctr, K);
  vq_main<<<N / TOK, 256, 0, stream>>>(z, cb, cb_bf, ee, mask, out_q,
                                       out_idx_f, out_loss, acc2, dctr, N / TOK, K);
}